// Round 3
// baseline (111.062 us; speedup 1.0000x reference)
//
#include <hip/hip_runtime.h>

// inputs (256,128,64) f32, mask (256,128) i32, qparams (4,2,10) f32,
// W (4,256,10) f32, b (4,256) f32.
// out f32: outputs(256,128,256) ++ hx(128,256) ++ cx(128,256).
#define T_LEN 256
#define BATCH 128
#define NQ 10
#define HID 256
#define OUT_HX (T_LEN * BATCH * HID)
#define OUT_CX (OUT_HX + BATCH * HID)
#define ZSTRIDE 40   // global z floats per (b,t): 10 n, gate-minor float4
#define ZROW 44      // padded LDS row stride (dwords)
#define TROW 65      // h-tile row stride (odd -> conflict-free both phases)

#define KS  (-1.44269504089f)   // -log2(e): sigmoid scale
#define KT2 (-2.88539008178f)   // -2*log2(e): tanh scale

// ---------------- K1: circuit z precompute ----------------
// One thread per (t,g). Math identical to the validated analytic DP.
// Gate exp2-scale folded into z here (sigmoid gates *KS, tanh gate *KT2);
// scanker scales bias to match, W stays raw.
__global__ __launch_bounds__(256) void zker(
    const float* __restrict__ inputs,
    const float* __restrict__ qparams,
    float* __restrict__ zws)
{
  const int b   = blockIdx.x;
  const int tq  = blockIdx.y;
  const int tid = threadIdx.x;
  const int t   = tq * 64 + (tid >> 2);
  const int g   = tid & 3;

  const float sg = (g == 2) ? KT2 : KS;

  float th0[NQ], cth[NQ], sth[NQ];
#pragma unroll
  for (int k = 0; k < NQ; ++k) {
    th0[k]   = qparams[g * 2 * NQ + k];
    float t1 = qparams[g * 2 * NQ + NQ + k];
    sth[k] = __sinf(t1);
    cth[k] = __cosf(t1);
  }
  float cphi[NQ], sphi[NQ];
  const float* xp = inputs + (t * BATCH + b) * 64;
#pragma unroll
  for (int k = 0; k < NQ; ++k) {
    float ang = xp[k] + th0[k];
    sphi[k] = __sinf(ang);
    cphi[k] = __cosf(ang);
  }
  float* zout = zws + (b * T_LEN + t) * ZSTRIDE + g;
#pragma unroll
  for (int w = 0; w < NQ; ++w) {
    float vI, vZ, vY, vX; int js;
    if (w == NQ - 1) { vI = 0.f; vZ = cth[NQ-1]; vY = sth[NQ-1]; vX = 0.f; js = NQ - 2; }
    else             { vI = 1.f; vZ = 0.f; vY = 0.f; vX = 0.f; js = w; }
#pragma unroll
    for (int j = js; j >= 0; --j) {
      float nI = cth[j] * (cphi[j+1] * vZ - sphi[j+1] * vY);
      float nZ = cth[j] * vI;
      float nY = sth[j] * vX;
      float nX = -sth[j] * (sphi[j+1] * vZ + cphi[j+1] * vY);
      vI = nI; vZ = nZ; vY = nY; vX = nX;
    }
    zout[w * 4] = (vI + cphi[0] * vZ - sphi[0] * vY) * sg;
  }
}

// ---------------- K2: parallel-scan LSTM, phase-split ----------------
// c_t = a_t*c_{t-1} + w_t with h-independent coefficients -> associative scan
// over t. Block = (b, 64-h group), 8 waves, wave owns 8 h, lane = t-in-round.
// Round body is phase-split so latency overlaps by construction:
//   A: gate coefficients (a,w,om) for all 8 hh -> regs (s_load waits overlap
//      across independent 40-FMA dots; bias hoisted out of r loop).
//   B: 8 scans interleaved by level (16 independent bpermutes per level ->
//      DS latency hidden 8-wide instead of exposed per-hh).
//   C: ct/carry/tanh/store per hh.
__global__ __launch_bounds__(512) void scanker(
    const float* __restrict__ zws,
    const int*  __restrict__ mask,
    const float* __restrict__ W,
    const float* __restrict__ bias,
    float* __restrict__ out)
{
  const int b    = blockIdx.x;      // 0..127
  const int h0   = blockIdx.y * 64; // h-group base
  const int tid  = threadIdx.x;     // 0..511
  const int lane = tid & 63;
  const int wavu = __builtin_amdgcn_readfirstlane(tid >> 6);  // provably uniform

  __shared__ float zlds[T_LEN * ZROW];   // 45056 B
  __shared__ float tlds[64 * TROW];      // 16640 B
  __shared__ float mk[T_LEN];            //  1024 B

  // stage z[b] (40KB) with padding; coalesced global float4 reads
  {
    const float4* zg = (const float4*)(zws + b * T_LEN * ZSTRIDE);
    for (int i = tid; i < T_LEN * 10; i += 512) {
      int t = i / 10, c4 = i - t * 10;
      *(float4*)&zlds[t * ZROW + c4 * 4] = zg[i];
    }
  }
  for (int t = tid; t < T_LEN; t += 512) mk[t] = (float)mask[t * BATCH + b];
  __syncthreads();

  // precomputed bpermute byte-addrs for shfl_up d = 1..32 (clamped low lanes)
  int srcA[6];
#pragma unroll
  for (int k = 0; k < 6; ++k) {
    const int d = 1 << k;
    srcA[k] = ((lane >= d) ? (lane - d) : lane) << 2;
  }

  // hoisted scaled biases (r-invariant, wave-uniform -> SGPRs)
  float bsc[8][4];
#pragma unroll
  for (int hh = 0; hh < 8; ++hh) {
    const int h = h0 + wavu * 8 + hh;
    bsc[hh][0] = bias[0 * HID + h] * KS;
    bsc[hh][1] = bias[1 * HID + h] * KS;
    bsc[hh][2] = bias[2 * HID + h] * KT2;
    bsc[hh][3] = bias[3 * HID + h] * KS;
  }

  float carry[8];
#pragma unroll
  for (int i = 0; i < 8; ++i) carry[i] = 0.f;

  for (int r = 0; r < 4; ++r) {
    const int t = r * 64 + lane;
    float4 z4[10];
#pragma unroll
    for (int n = 0; n < NQ; ++n) z4[n] = *(const float4*)&zlds[t * ZROW + n * 4];
    const float m = mk[t];
    const float onem = 1.f - m;

    // ---- phase A: gate coefficients for all 8 hh ----
    float a8[8], w8[8], om8[8];
#pragma unroll
    for (int hh = 0; hh < 8; ++hh) {
      const int h = h0 + wavu * 8 + hh;
      const int wb = __builtin_amdgcn_readfirstlane(h * NQ);  // uniform W row base

      float p0 = bsc[hh][0];
      float p1 = bsc[hh][1];
      float p2 = bsc[hh][2];
      float p3 = bsc[hh][3];
#pragma unroll
      for (int n = 0; n < NQ; ++n) {
        p0 = fmaf(z4[n].x, W[0 * HID * NQ + wb + n], p0);
        p1 = fmaf(z4[n].y, W[1 * HID * NQ + wb + n], p1);
        p2 = fmaf(z4[n].z, W[2 * HID * NQ + wb + n], p2);
        p3 = fmaf(z4[n].w, W[3 * HID * NQ + wb + n], p3);
      }
      const float uf = __builtin_amdgcn_rcpf(1.f + __builtin_amdgcn_exp2f(p0));
      const float ui = __builtin_amdgcn_rcpf(1.f + __builtin_amdgcn_exp2f(p1));
      const float ug = __builtin_amdgcn_rcpf(1.f + __builtin_amdgcn_exp2f(p2));
      const float uo = __builtin_amdgcn_rcpf(1.f + __builtin_amdgcn_exp2f(p3));

      a8[hh]  = fmaf(m, uf, onem);                     // decay a_t
      w8[hh]  = m * ui * fmaf(2.f, ug, -1.f);          // input w_t (m*m==m)
      om8[hh] = fmaf(m, uo, onem);
    }

    // ---- phase B: 8 interleaved Hillis-Steele scans ----
#pragma unroll
    for (int k = 0; k < 6; ++k) {
      const int d = 1 << k;
      const bool p = (lane >= d);
#pragma unroll
      for (int hh = 0; hh < 8; ++hh) {
        float au = __int_as_float(
            __builtin_amdgcn_ds_bpermute(srcA[k], __float_as_int(a8[hh])));
        float wu = __int_as_float(
            __builtin_amdgcn_ds_bpermute(srcA[k], __float_as_int(w8[hh])));
        au = p ? au : 1.f;
        wu = p ? wu : 0.f;
        w8[hh] = fmaf(a8[hh], wu, w8[hh]);
        a8[hh] = a8[hh] * au;
      }
    }

    // ---- phase C: carry, tanh, stores ----
#pragma unroll
    for (int hh = 0; hh < 8; ++hh) {
      const float ct = fmaf(a8[hh], carry[hh], w8[hh]);
      carry[hh] = __shfl(ct, 63, 64);

      const float ec = __builtin_amdgcn_exp2f(ct * KT2);
      const float tc = fmaf(2.f, __builtin_amdgcn_rcpf(1.f + ec), -1.f);
      const float hv = om8[hh] * tc;

      tlds[lane * TROW + wavu * 8 + hh] = hv;

      if (r == 3 && lane == 63) {
        const int h = h0 + wavu * 8 + hh;
        out[OUT_HX + b * HID + h] = hv;
        out[OUT_CX + b * HID + h] = ct;
      }
    }
    __syncthreads();
    // coalesced writeout: 64 t x 64 h tile, 256B contiguous per t
#pragma unroll
    for (int s = 0; s < 2; ++s) {
      const int q = tid + s * 512;          // 0..1023
      const int tt = q >> 4, c = q & 15;
      float4 v;
      v.x = tlds[tt * TROW + 4 * c + 0];
      v.y = tlds[tt * TROW + 4 * c + 1];
      v.z = tlds[tt * TROW + 4 * c + 2];
      v.w = tlds[tt * TROW + 4 * c + 3];
      *(float4*)&out[(r * 64 + tt) * (BATCH * HID) + b * HID + h0 + 4 * c] = v;
    }
    __syncthreads();
  }
}

extern "C" void kernel_launch(void* const* d_in, const int* in_sizes, int n_in,
                              void* d_out, int out_size, void* d_ws, size_t ws_size,
                              hipStream_t stream)
{
  // identify arrays by unique element counts (order-proof)
  int ii = 0, im = 1, iq = 2, iw = 3, ib = 4;
  for (int i = 0; i < n_in; ++i) {
    switch (in_sizes[i]) {
      case 2097152: ii = i; break;   // inputs (256,128,64)
      case 32768:   im = i; break;   // mask (256,128)
      case 80:      iq = i; break;   // qparams (4,2,10)
      case 10240:   iw = i; break;   // W (4,256,10)
      case 1024:    ib = i; break;   // b (4,256)
      default: break;
    }
  }
  const float* inputs  = (const float*)d_in[ii];
  const int*   mask    = (const int*)d_in[im];
  const float* qparams = (const float*)d_in[iq];
  const float* W       = (const float*)d_in[iw];
  const float* bias    = (const float*)d_in[ib];
  float*       out     = (float*)d_out;
  float*       zws     = (float*)d_ws;   // needs 128*256*40*4 = 5.25 MB

  zker<<<dim3(BATCH, 4), dim3(256), 0, stream>>>(inputs, qparams, zws);
  scanker<<<dim3(BATCH, 4), dim3(512), 0, stream>>>(zws, mask, W, bias, out);
}

// Round 4
// 108.804 us; speedup vs baseline: 1.0207x; 1.0207x over previous
//
#include <hip/hip_runtime.h>

// inputs (256,128,64) f32, mask (256,128) i32, qparams (4,2,10) f32,
// W (4,256,10) f32, b (4,256) f32.
// out f32: outputs(256,128,256) ++ hx(128,256) ++ cx(128,256).
#define T_LEN 256
#define BATCH 128
#define NQ 10
#define HID 256
#define OUT_HX (T_LEN * BATCH * HID)
#define OUT_CX (OUT_HX + BATCH * HID)
#define TROW 65      // h-tile row stride (odd -> conflict-free both phases)

#define KS  (-1.44269504089f)   // -log2(e): sigmoid scale
#define KT2 (-2.88539008178f)   // -2*log2(e): tanh scale

// ---------------- K1: circuit z precompute ----------------
// One thread per (t,g). Math identical to the validated analytic DP.
// Gate exp2-scale folded into z (sigmoid gates *KS, tanh gate *KT2).
// NEW layout: zws[b][n][t][g] (float4 over g) -> zker wave writes are
// byte-linear (lane l -> +4*l), scanker staging is a linear float4 copy,
// and scanker's per-round reads are conflict-free.
__global__ __launch_bounds__(256) void zker(
    const float* __restrict__ inputs,
    const float* __restrict__ qparams,
    float* __restrict__ zws)
{
  const int b   = blockIdx.x;
  const int tq  = blockIdx.y;
  const int tid = threadIdx.x;
  const int t   = tq * 64 + (tid >> 2);
  const int g   = tid & 3;

  const float sg = (g == 2) ? KT2 : KS;

  float th0[NQ], cth[NQ], sth[NQ];
#pragma unroll
  for (int k = 0; k < NQ; ++k) {
    th0[k]   = qparams[g * 2 * NQ + k];
    float t1 = qparams[g * 2 * NQ + NQ + k];
    sth[k] = __sinf(t1);
    cth[k] = __cosf(t1);
  }
  float cphi[NQ], sphi[NQ];
  const float* xp = inputs + (t * BATCH + b) * 64;
#pragma unroll
  for (int k = 0; k < NQ; ++k) {
    float ang = xp[k] + th0[k];
    sphi[k] = __sinf(ang);
    cphi[k] = __cosf(ang);
  }
  float* zout = zws + (b * NQ * T_LEN + t) * 4 + g;   // + w*T_LEN*4 per qubit
#pragma unroll
  for (int w = 0; w < NQ; ++w) {
    float vI, vZ, vY, vX; int js;
    if (w == NQ - 1) { vI = 0.f; vZ = cth[NQ-1]; vY = sth[NQ-1]; vX = 0.f; js = NQ - 2; }
    else             { vI = 1.f; vZ = 0.f; vY = 0.f; vX = 0.f; js = w; }
#pragma unroll
    for (int j = js; j >= 0; --j) {
      float nI = cth[j] * (cphi[j+1] * vZ - sphi[j+1] * vY);
      float nZ = cth[j] * vI;
      float nY = sth[j] * vX;
      float nX = -sth[j] * (sphi[j+1] * vZ + cphi[j+1] * vY);
      vI = nI; vZ = nZ; vY = nY; vX = nX;
    }
    zout[w * T_LEN * 4] = (vI + cphi[0] * vZ - sphi[0] * vY) * sg;
  }
}

// ---------------- K2: parallel-scan LSTM ----------------
// c_t = a_t*c_{t-1} + w_t with h-independent coefficients -> associative scan
// over t. Block = (b, 64-h group), 8 waves, wave owns 8 h, lane = t-in-round.
// z staged in LDS as [n][t] float4 -> ds_read_b128 reads 1KB contiguous per
// wave (conflict-free; old [t][n] layout was 176B lane stride = 8-way
// conflict on the hottest LDS op). tlds ping-pong -> 1 barrier/round.
// Round body software-pipelined: GATE(4..7) interleaved into scan levels of
// hh 0..3; CPHASE(0..3) interleaved into scan levels of hh 4..7.

#define GATEBODY(HH)                                                     \
  {                                                                      \
    const int h_ = h0 + wavu * 8 + (HH);                                 \
    const int wb_ = __builtin_amdgcn_readfirstlane(h_ * NQ);             \
    float p0 = bsc[HH][0], p1 = bsc[HH][1], p2 = bsc[HH][2], p3 = bsc[HH][3]; \
    _Pragma("unroll")                                                    \
    for (int n = 0; n < NQ; ++n) {                                       \
      p0 = fmaf(z4[n].x, W[0 * HID * NQ + wb_ + n], p0);                 \
      p1 = fmaf(z4[n].y, W[1 * HID * NQ + wb_ + n], p1);                 \
      p2 = fmaf(z4[n].z, W[2 * HID * NQ + wb_ + n], p2);                 \
      p3 = fmaf(z4[n].w, W[3 * HID * NQ + wb_ + n], p3);                 \
    }                                                                    \
    const float uf = __builtin_amdgcn_rcpf(1.f + __builtin_amdgcn_exp2f(p0)); \
    const float ui = __builtin_amdgcn_rcpf(1.f + __builtin_amdgcn_exp2f(p1)); \
    const float ug = __builtin_amdgcn_rcpf(1.f + __builtin_amdgcn_exp2f(p2)); \
    const float uo = __builtin_amdgcn_rcpf(1.f + __builtin_amdgcn_exp2f(p3)); \
    a8[HH]  = fmaf(m, uf, onem);                                         \
    w8[HH]  = m * ui * fmaf(2.f, ug, -1.f);                              \
    om8[HH] = fmaf(m, uo, onem);                                         \
  }

#define BP(SRC, V) __int_as_float(__builtin_amdgcn_ds_bpermute((SRC), __float_as_int(V)))

#define SCANLEV1(K, HH)                                                  \
  {                                                                      \
    float au = BP(srcA[K], a8[HH]);                                      \
    float wu = BP(srcA[K], w8[HH]);                                      \
    au = pm[K] ? au : 1.f;                                               \
    wu = pm[K] ? wu : 0.f;                                               \
    w8[HH] = fmaf(a8[HH], wu, w8[HH]);                                   \
    a8[HH] = a8[HH] * au;                                                \
  }

#define SCANLEV4(K, H0, H1, H2, H3)                                      \
  SCANLEV1(K, H0) SCANLEV1(K, H1) SCANLEV1(K, H2) SCANLEV1(K, H3)

#define CPHASE(HH)                                                       \
  {                                                                      \
    const float ct = fmaf(a8[HH], carry[HH], w8[HH]);                    \
    carry[HH] = __shfl(ct, 63, 64);                                      \
    const float ec = __builtin_amdgcn_exp2f(ct * KT2);                   \
    const float tc = fmaf(2.f, __builtin_amdgcn_rcpf(1.f + ec), -1.f);   \
    const float hv = om8[HH] * tc;                                       \
    tlds[p][lane * TROW + wavu * 8 + (HH)] = hv;                         \
    if (r == 3 && lane == 63) {                                          \
      const int h_ = h0 + wavu * 8 + (HH);                               \
      out[OUT_HX + b * HID + h_] = hv;                                   \
      out[OUT_CX + b * HID + h_] = ct;                                   \
    }                                                                    \
  }

__global__ __launch_bounds__(512) void scanker(
    const float* __restrict__ zws,
    const int*  __restrict__ mask,
    const float* __restrict__ W,
    const float* __restrict__ bias,
    float* __restrict__ out)
{
  const int b    = blockIdx.x;      // 0..127
  const int h0   = blockIdx.y * 64; // h-group base
  const int tid  = threadIdx.x;     // 0..511
  const int lane = tid & 63;
  const int wavu = __builtin_amdgcn_readfirstlane(tid >> 6);  // provably uniform

  __shared__ float4 zl4[NQ * T_LEN];     // 40960 B, [n][t]
  __shared__ float  tlds[2][64 * TROW];  // 2 x 16640 B (ping-pong)
  __shared__ float  mk[T_LEN];           //  1024 B

  // stage z[b] (40KB): pure linear float4 copy, coalesced both sides
  {
    const float4* zg = (const float4*)(zws + b * NQ * T_LEN * 4);
    for (int i = tid; i < NQ * T_LEN; i += 512) zl4[i] = zg[i];
  }
  for (int t = tid; t < T_LEN; t += 512) mk[t] = (float)mask[t * BATCH + b];
  __syncthreads();

  // precomputed bpermute byte-addrs + predicates for shfl_up d = 1..32
  int srcA[6]; bool pm[6];
#pragma unroll
  for (int k = 0; k < 6; ++k) {
    const int d = 1 << k;
    pm[k]   = (lane >= d);
    srcA[k] = ((lane >= d) ? (lane - d) : lane) << 2;
  }

  // hoisted scaled biases (wave-uniform -> SGPRs)
  float bsc[8][4];
#pragma unroll
  for (int hh = 0; hh < 8; ++hh) {
    const int h = h0 + wavu * 8 + hh;
    bsc[hh][0] = bias[0 * HID + h] * KS;
    bsc[hh][1] = bias[1 * HID + h] * KS;
    bsc[hh][2] = bias[2 * HID + h] * KT2;
    bsc[hh][3] = bias[3 * HID + h] * KS;
  }

  float carry[8];
#pragma unroll
  for (int i = 0; i < 8; ++i) carry[i] = 0.f;

  for (int r = 0; r < 4; ++r) {
    const int p = r & 1;
    const int t = r * 64 + lane;
    float4 z4[NQ];
#pragma unroll
    for (int n = 0; n < NQ; ++n) z4[n] = zl4[n * T_LEN + t];
    const float m = mk[t];
    const float onem = 1.f - m;

    float a8[8], w8[8], om8[8];

    // ---- pipelined round body ----
    GATEBODY(0) GATEBODY(1) GATEBODY(2) GATEBODY(3)
    SCANLEV4(0, 0, 1, 2, 3) GATEBODY(4)
    SCANLEV4(1, 0, 1, 2, 3) GATEBODY(5)
    SCANLEV4(2, 0, 1, 2, 3) GATEBODY(6)
    SCANLEV4(3, 0, 1, 2, 3) GATEBODY(7)
    SCANLEV4(4, 0, 1, 2, 3)
    SCANLEV4(5, 0, 1, 2, 3)
    SCANLEV4(0, 4, 5, 6, 7) CPHASE(0)
    SCANLEV4(1, 4, 5, 6, 7) CPHASE(1)
    SCANLEV4(2, 4, 5, 6, 7) CPHASE(2)
    SCANLEV4(3, 4, 5, 6, 7) CPHASE(3)
    SCANLEV4(4, 4, 5, 6, 7)
    SCANLEV4(5, 4, 5, 6, 7)
    CPHASE(4) CPHASE(5) CPHASE(6) CPHASE(7)

    __syncthreads();   // tlds[p] complete; 1-dbuf ping-pong needs only this
    // coalesced writeout: 64 t x 64 h tile, 256B contiguous per t
#pragma unroll
    for (int s = 0; s < 2; ++s) {
      const int q = tid + s * 512;          // 0..1023
      const int tt = q >> 4, c = q & 15;
      float4 v;
      v.x = tlds[p][tt * TROW + 4 * c + 0];
      v.y = tlds[p][tt * TROW + 4 * c + 1];
      v.z = tlds[p][tt * TROW + 4 * c + 2];
      v.w = tlds[p][tt * TROW + 4 * c + 3];
      *(float4*)&out[(r * 64 + tt) * (BATCH * HID) + b * HID + h0 + 4 * c] = v;
    }
    // no second barrier: next round writes tlds[1-p], whose last readers
    // (round r-1 writeout) must have passed this round's barrier already
  }
}

extern "C" void kernel_launch(void* const* d_in, const int* in_sizes, int n_in,
                              void* d_out, int out_size, void* d_ws, size_t ws_size,
                              hipStream_t stream)
{
  // identify arrays by unique element counts (order-proof)
  int ii = 0, im = 1, iq = 2, iw = 3, ib = 4;
  for (int i = 0; i < n_in; ++i) {
    switch (in_sizes[i]) {
      case 2097152: ii = i; break;   // inputs (256,128,64)
      case 32768:   im = i; break;   // mask (256,128)
      case 80:      iq = i; break;   // qparams (4,2,10)
      case 10240:   iw = i; break;   // W (4,256,10)
      case 1024:    ib = i; break;   // b (4,256)
      default: break;
    }
  }
  const float* inputs  = (const float*)d_in[ii];
  const int*   mask    = (const int*)d_in[im];
  const float* qparams = (const float*)d_in[iq];
  const float* W       = (const float*)d_in[iw];
  const float* bias    = (const float*)d_in[ib];
  float*       out     = (float*)d_out;
  float*       zws     = (float*)d_ws;   // needs 128*10*256*4*4 = 5.25 MB

  zker<<<dim3(BATCH, 4), dim3(256), 0, stream>>>(inputs, qparams, zws);
  scanker<<<dim3(BATCH, 4), dim3(512), 0, stream>>>(zws, mask, W, bias, out);
}

// Round 5
// 106.673 us; speedup vs baseline: 1.0411x; 1.0200x over previous
//
#include <hip/hip_runtime.h>

// inputs (256,128,64) f32, mask (256,128) i32, qparams (4,2,10) f32,
// W (4,256,10) f32, b (4,256) f32.
// out f32: outputs(256,128,256) ++ hx(128,256) ++ cx(128,256).
#define T_LEN 256
#define BATCH 128
#define NQ 10
#define HID 256
#define OUT_HX (T_LEN * BATCH * HID)
#define OUT_CX (OUT_HX + BATCH * HID)
#define TROW 33      // 32-h tile row stride (odd -> conflict-free both phases)

#define KS  (-1.44269504089f)   // -log2(e): sigmoid scale
#define KT2 (-2.88539008178f)   // -2*log2(e): tanh scale

// ---------------- K1: circuit z precompute ----------------
// One thread per (t,g). Math identical to the validated analytic DP.
// Gate exp2-scale folded into z (sigmoid gates *KS, tanh gate *KT2).
// Layout zws[b][n][t][g] (float4 over g): zker writes byte-linear,
// scanker reads 1KB contiguous per (n, wave) -> perfectly coalesced.
__global__ __launch_bounds__(256) void zker(
    const float* __restrict__ inputs,
    const float* __restrict__ qparams,
    float* __restrict__ zws)
{
  const int b   = blockIdx.x;
  const int tq  = blockIdx.y;
  const int tid = threadIdx.x;
  const int t   = tq * 64 + (tid >> 2);
  const int g   = tid & 3;

  const float sg = (g == 2) ? KT2 : KS;

  float th0[NQ], cth[NQ], sth[NQ];
#pragma unroll
  for (int k = 0; k < NQ; ++k) {
    th0[k]   = qparams[g * 2 * NQ + k];
    float t1 = qparams[g * 2 * NQ + NQ + k];
    sth[k] = __sinf(t1);
    cth[k] = __cosf(t1);
  }
  float cphi[NQ], sphi[NQ];
  const float* xp = inputs + (t * BATCH + b) * 64;
#pragma unroll
  for (int k = 0; k < NQ; ++k) {
    float ang = xp[k] + th0[k];
    sphi[k] = __sinf(ang);
    cphi[k] = __cosf(ang);
  }
  float* zout = zws + (b * NQ * T_LEN + t) * 4 + g;   // + w*T_LEN*4 per qubit
#pragma unroll
  for (int w = 0; w < NQ; ++w) {
    float vI, vZ, vY, vX; int js;
    if (w == NQ - 1) { vI = 0.f; vZ = cth[NQ-1]; vY = sth[NQ-1]; vX = 0.f; js = NQ - 2; }
    else             { vI = 1.f; vZ = 0.f; vY = 0.f; vX = 0.f; js = w; }
#pragma unroll
    for (int j = js; j >= 0; --j) {
      float nI = cth[j] * (cphi[j+1] * vZ - sphi[j+1] * vY);
      float nZ = cth[j] * vI;
      float nY = sth[j] * vX;
      float nX = -sth[j] * (sphi[j+1] * vZ + cphi[j+1] * vY);
      vI = nI; vZ = nZ; vY = nY; vX = nX;
    }
    zout[w * T_LEN * 4] = (vI + cphi[0] * vZ - sphi[0] * vY) * sg;
  }
}

// ---------------- K2: parallel-scan LSTM, occupancy-first ----------------
// c_t = a_t*c_{t-1} + w_t, h-independent coefficients -> associative scan.
// R2-R4 all plateaued at ~43us with VALUBusy 43%: latency-bound at the hard
// 2-blocks/CU cap (75KB LDS, 512-block grid). This version: no z LDS staging
// (all waves read the same coalesced z[b] slice -> global/L2 direct), 8
// h-groups of 32 (grid 1024 = 4 blocks/CU), n-chunked gate phase to keep
// VGPR <= 64. Target 8 waves/SIMD (4x latency hiding).
__global__ __launch_bounds__(512) void scanker(
    const float* __restrict__ zws,
    const int*  __restrict__ mask,
    const float* __restrict__ W,
    const float* __restrict__ bias,
    float* __restrict__ out)
{
  const int b    = blockIdx.x;      // 0..127
  const int h0   = blockIdx.y * 32; // h-group base (8 groups)
  const int tid  = threadIdx.x;     // 0..511
  const int lane = tid & 63;
  const int wavu = __builtin_amdgcn_readfirstlane(tid >> 6);  // provably uniform

  __shared__ float tlds[2][64 * TROW];  // 2 x 8448 B (ping-pong)
  __shared__ float mk[T_LEN];           // 1024 B

  for (int t = tid; t < T_LEN; t += 512) mk[t] = (float)mask[t * BATCH + b];
  __syncthreads();

  // precomputed bpermute byte-addrs + predicates for shfl_up d = 1..32
  int srcA[6]; bool pm[6];
#pragma unroll
  for (int k = 0; k < 6; ++k) {
    const int d = 1 << k;
    pm[k]   = (lane >= d);
    srcA[k] = ((lane >= d) ? (lane - d) : lane) << 2;
  }

  // hoisted scaled biases (wave-uniform -> SGPRs)
  float bsc[4][4];
#pragma unroll
  for (int hh = 0; hh < 4; ++hh) {
    const int h = __builtin_amdgcn_readfirstlane(h0 + wavu * 4 + hh);
    bsc[hh][0] = bias[0 * HID + h] * KS;
    bsc[hh][1] = bias[1 * HID + h] * KS;
    bsc[hh][2] = bias[2 * HID + h] * KT2;
    bsc[hh][3] = bias[3 * HID + h] * KS;
  }

  float carry[4];
#pragma unroll
  for (int i = 0; i < 4; ++i) carry[i] = 0.f;

  const float4* zg = (const float4*)zws + b * NQ * T_LEN;

  for (int r = 0; r < 4; ++r) {
    const int p = r & 1;
    const int t = r * 64 + lane;
    const float m = mk[t];
    const float onem = 1.f - m;

    // ---- gate phase, n-chunked: one z float4 feeds 16 accumulators ----
    float acc[4][4];
#pragma unroll
    for (int hh = 0; hh < 4; ++hh) {
      acc[hh][0] = bsc[hh][0]; acc[hh][1] = bsc[hh][1];
      acc[hh][2] = bsc[hh][2]; acc[hh][3] = bsc[hh][3];
    }
#pragma unroll
    for (int n = 0; n < NQ; ++n) {
      const float4 z = zg[n * T_LEN + t];   // coalesced, L1/L2-served
#pragma unroll
      for (int hh = 0; hh < 4; ++hh) {
        const int wb = __builtin_amdgcn_readfirstlane((h0 + wavu * 4 + hh) * NQ + n);
        acc[hh][0] = fmaf(z.x, W[0 * HID * NQ + wb], acc[hh][0]);
        acc[hh][1] = fmaf(z.y, W[1 * HID * NQ + wb], acc[hh][1]);
        acc[hh][2] = fmaf(z.z, W[2 * HID * NQ + wb], acc[hh][2]);
        acc[hh][3] = fmaf(z.w, W[3 * HID * NQ + wb], acc[hh][3]);
      }
    }

    float a4[4], w4[4], om4[4];
#pragma unroll
    for (int hh = 0; hh < 4; ++hh) {
      const float uf = __builtin_amdgcn_rcpf(1.f + __builtin_amdgcn_exp2f(acc[hh][0]));
      const float ui = __builtin_amdgcn_rcpf(1.f + __builtin_amdgcn_exp2f(acc[hh][1]));
      const float ug = __builtin_amdgcn_rcpf(1.f + __builtin_amdgcn_exp2f(acc[hh][2]));
      const float uo = __builtin_amdgcn_rcpf(1.f + __builtin_amdgcn_exp2f(acc[hh][3]));
      a4[hh]  = fmaf(m, uf, onem);                 // decay a_t
      w4[hh]  = m * ui * fmaf(2.f, ug, -1.f);      // input w_t (m*m==m)
      om4[hh] = fmaf(m, uo, onem);
    }

    // ---- 4 interleaved Hillis-Steele scans over 64 t-lanes ----
#pragma unroll
    for (int k = 0; k < 6; ++k) {
#pragma unroll
      for (int hh = 0; hh < 4; ++hh) {
        float au = __int_as_float(
            __builtin_amdgcn_ds_bpermute(srcA[k], __float_as_int(a4[hh])));
        float wu = __int_as_float(
            __builtin_amdgcn_ds_bpermute(srcA[k], __float_as_int(w4[hh])));
        au = pm[k] ? au : 1.f;
        wu = pm[k] ? wu : 0.f;
        w4[hh] = fmaf(a4[hh], wu, w4[hh]);
        a4[hh] = a4[hh] * au;
      }
    }

    // ---- carry, tanh, store ----
#pragma unroll
    for (int hh = 0; hh < 4; ++hh) {
      const float ct = fmaf(a4[hh], carry[hh], w4[hh]);
      carry[hh] = __shfl(ct, 63, 64);
      const float ec = __builtin_amdgcn_exp2f(ct * KT2);
      const float tc = fmaf(2.f, __builtin_amdgcn_rcpf(1.f + ec), -1.f);
      const float hv = om4[hh] * tc;
      tlds[p][lane * TROW + wavu * 4 + hh] = hv;
      if (r == 3 && lane == 63) {
        const int h = h0 + wavu * 4 + hh;
        out[OUT_HX + b * HID + h] = hv;
        out[OUT_CX + b * HID + h] = ct;
      }
    }

    __syncthreads();   // tlds[p] complete; ping-pong needs only this barrier
    // coalesced writeout: 64 t x 32 h tile, 128B contiguous per t
    {
      const int tt = tid >> 3, c = tid & 7;   // 64 t x 8 float4-cols
      float4 v;
      v.x = tlds[p][tt * TROW + 4 * c + 0];
      v.y = tlds[p][tt * TROW + 4 * c + 1];
      v.z = tlds[p][tt * TROW + 4 * c + 2];
      v.w = tlds[p][tt * TROW + 4 * c + 3];
      *(float4*)&out[(r * 64 + tt) * (BATCH * HID) + b * HID + h0 + 4 * c] = v;
    }
    // no second barrier: next round writes tlds[1-p], whose readers passed
    // this barrier already
  }
}

extern "C" void kernel_launch(void* const* d_in, const int* in_sizes, int n_in,
                              void* d_out, int out_size, void* d_ws, size_t ws_size,
                              hipStream_t stream)
{
  // identify arrays by unique element counts (order-proof)
  int ii = 0, im = 1, iq = 2, iw = 3, ib = 4;
  for (int i = 0; i < n_in; ++i) {
    switch (in_sizes[i]) {
      case 2097152: ii = i; break;   // inputs (256,128,64)
      case 32768:   im = i; break;   // mask (256,128)
      case 80:      iq = i; break;   // qparams (4,2,10)
      case 10240:   iw = i; break;   // W (4,256,10)
      case 1024:    ib = i; break;   // b (4,256)
      default: break;
    }
  }
  const float* inputs  = (const float*)d_in[ii];
  const int*   mask    = (const int*)d_in[im];
  const float* qparams = (const float*)d_in[iq];
  const float* W       = (const float*)d_in[iw];
  const float* bias    = (const float*)d_in[ib];
  float*       out     = (float*)d_out;
  float*       zws     = (float*)d_ws;   // needs 128*10*256*4*4 = 5.25 MB

  zker<<<dim3(BATCH, 4), dim3(256), 0, stream>>>(inputs, qparams, zws);
  scanker<<<dim3(BATCH, 8), dim3(512), 0, stream>>>(zws, mask, W, bias, out);
}